// Round 1
// baseline (1162.273 us; speedup 1.0000x reference)
//
#include <hip/hip_runtime.h>
#include <math.h>

// NSVQ: N=262144 rows, D=64, K=1024 codebooks.
// Outputs concatenated in d_out (float32): [N*D] quantized | [1] perplexity | [K] counts_new.

#define NROWS 262144
#define DIM 64
#define KCODES 1024
#define ND ((size_t)NROWS * DIM)

// --- kernel 0: per-codebook squared norms -------------------------------
__global__ void nsvq_cnorm(const float* __restrict__ cb, float* __restrict__ cnorm) {
    int k = blockIdx.x * blockDim.x + threadIdx.x;
    if (k >= KCODES) return;
    const float4* c4 = (const float4*)(cb + (size_t)k * DIM);
    float s = 0.f;
#pragma unroll
    for (int j = 0; j < DIM / 4; ++j) {
        float4 c = c4[j];
        s = fmaf(c.x, c.x, s);
        s = fmaf(c.y, c.y, s);
        s = fmaf(c.z, c.z, s);
        s = fmaf(c.w, c.w, s);
    }
    cnorm[k] = s;
}

// --- kernel 1: per-row argmin + NSVQ output + histogram -----------------
__global__ __launch_bounds__(256) void nsvq_main(
    const float* __restrict__ x, const float* __restrict__ rv,
    const float* __restrict__ cb, const float* __restrict__ cnorm,
    float* __restrict__ out, unsigned int* __restrict__ counts)
{
    const int row = blockIdx.x * 256 + threadIdx.x;
    const float4* xp = (const float4*)(x + (size_t)row * DIM);
    float4 xr[16];
#pragma unroll
    for (int j = 0; j < 16; ++j) xr[j] = xp[j];

    float best = 3.4e38f;
    int bestk = 0;
    // k is wave-uniform -> codebook loads are uniform-address (scalar path).
#pragma unroll 2
    for (int k = 0; k < KCODES; ++k) {
        const float4* cp = (const float4*)(cb + (size_t)k * DIM);
        float acc[8];
#pragma unroll
        for (int t = 0; t < 8; ++t) acc[t] = 0.f;
#pragma unroll
        for (int j = 0; j < 16; ++j) {
            float4 c = cp[j];
            float4 v = xr[j];
            float t = acc[j & 7];
            t = fmaf(v.x, c.x, t);
            t = fmaf(v.y, c.y, t);
            t = fmaf(v.z, c.z, t);
            t = fmaf(v.w, c.w, t);
            acc[j & 7] = t;
        }
        float dot = ((acc[0] + acc[1]) + (acc[2] + acc[3])) +
                    ((acc[4] + acc[5]) + (acc[6] + acc[7]));
        float dist = fmaf(-2.f, dot, cnorm[k]);  // ||c||^2 - 2 x.c  (row-constant ||x||^2 dropped)
        if (dist < best) { best = dist; bestk = k; }  // strict < keeps first min (np.argmin tie rule)
    }

    // ||x||^2
    float xx = 0.f;
#pragma unroll
    for (int j = 0; j < 16; ++j) {
        float4 v = xr[j];
        xx = fmaf(v.x, v.x, xx);
        xx = fmaf(v.y, v.y, xx);
        xx = fmaf(v.z, v.z, xx);
        xx = fmaf(v.w, v.w, xx);
    }
    float res2 = xx + best;          // = ||x - c_best||^2
    if (res2 < 0.f) res2 = 0.f;
    float resn = sqrtf(res2);

    // random vector norm + output
    const float4* rvp = (const float4*)(rv + (size_t)row * DIM);
    float4 rr[16];
    float rn2 = 0.f;
#pragma unroll
    for (int j = 0; j < 16; ++j) {
        float4 r = rvp[j];
        rr[j] = r;
        rn2 = fmaf(r.x, r.x, rn2);
        rn2 = fmaf(r.y, r.y, rn2);
        rn2 = fmaf(r.z, r.z, rn2);
        rn2 = fmaf(r.w, r.w, rn2);
    }
    float scale = resn / (sqrtf(rn2) + 1e-12f);

    float4* op = (float4*)(out + (size_t)row * DIM);
#pragma unroll
    for (int j = 0; j < 16; ++j) {
        float4 v = xr[j];
        float4 r = rr[j];
        float4 o;
        o.x = fmaf(scale, r.x, v.x);
        o.y = fmaf(scale, r.y, v.y);
        o.z = fmaf(scale, r.z, v.z);
        o.w = fmaf(scale, r.w, v.w);
        op[j] = o;
    }

    atomicAdd(&counts[bestk], 1u);
}

// --- kernel 2: perplexity + counts output -------------------------------
__global__ void nsvq_finalize(const unsigned int* __restrict__ counts,
                              const int* __restrict__ used,
                              float* __restrict__ out)
{
    const int k = threadIdx.x;  // 1024 threads, 16 waves
    const unsigned c = counts[k];
    float avg = (float)c * (1.0f / (float)NROWS);
    float term = (c > 0) ? (-avg * logf(avg + 1e-12f)) : 0.0f;

    // wave reduce (64 lanes)
    float v = term;
#pragma unroll
    for (int off = 32; off > 0; off >>= 1) v += __shfl_down(v, off, 64);

    __shared__ float partial[16];
    if ((threadIdx.x & 63) == 0) partial[threadIdx.x >> 6] = v;
    __syncthreads();

    if (threadIdx.x < 64) {
        float s = (threadIdx.x < 16) ? partial[threadIdx.x] : 0.0f;
#pragma unroll
        for (int off = 32; off > 0; off >>= 1) s += __shfl_down(s, off, 64);
        if (threadIdx.x == 0) out[ND] = expf(s);
    }

    out[ND + 1 + k] = (float)(c + (unsigned)used[k]);
}

extern "C" void kernel_launch(void* const* d_in, const int* in_sizes, int n_in,
                              void* d_out, int out_size, void* d_ws, size_t ws_size,
                              hipStream_t stream) {
    const float* x    = (const float*)d_in[0];
    const float* rv   = (const float*)d_in[1];
    const float* cb   = (const float*)d_in[2];
    const int*   used = (const int*)d_in[3];
    float* out = (float*)d_out;

    float*        cnorm  = (float*)d_ws;
    unsigned int* counts = (unsigned int*)((char*)d_ws + KCODES * sizeof(float));

    hipMemsetAsync(counts, 0, KCODES * sizeof(unsigned int), stream);
    nsvq_cnorm<<<(KCODES + 255) / 256, 256, 0, stream>>>(cb, cnorm);
    nsvq_main<<<NROWS / 256, 256, 0, stream>>>(x, rv, cb, cnorm, out, counts);
    nsvq_finalize<<<1, KCODES, 0, stream>>>(counts, used, out);
}

// Round 2
// 691.446 us; speedup vs baseline: 1.6809x; 1.6809x over previous
//
#include <hip/hip_runtime.h>
#include <math.h>

// NSVQ: N=262144 rows, D=64, K=1024 codebooks.
// d_out (fp32): [N*D] quantized | [1] perplexity | [K] counts_new.
//
// Strategy: argmin_k(||c||^2 - 2 x.c) via bf16 hi/lo-split MFMA (3 passes:
// hi*hi + hi*lo + lo*hi => ~1e-5 abs dot error, fp32-reassociation-class),
// then a memory-bound epilogue recomputing ||x - c_best||^2 in exact fp32.

#define NROWS 262144
#define DIM 64
#define KCODES 1024
#define ND ((size_t)NROWS * DIM)

typedef __attribute__((ext_vector_type(8))) short bf16x8;   // 8 bf16 in 4 VGPRs
typedef __attribute__((ext_vector_type(4))) float f32x4;

__device__ inline short f2bf(float f) {             // RNE fp32 -> bf16
    unsigned u = __builtin_bit_cast(unsigned, f);
    unsigned r = (u + 0x7FFFu + ((u >> 16) & 1u)) >> 16;
    return (short)r;
}
__device__ inline float bf2f(short h) {
    unsigned u = ((unsigned)(unsigned short)h) << 16;
    return __builtin_bit_cast(float, u);
}

// --- prep: per-code hi/lo bf16 split + fp32 squared norm ----------------
__global__ void nsvq_prep(const float* __restrict__ cb,
                          short* __restrict__ cbh, short* __restrict__ cbl,
                          float* __restrict__ cnorm) {
    int k = blockIdx.x * blockDim.x + threadIdx.x;
    if (k >= KCODES) return;
    const float* row = cb + (size_t)k * DIM;
    float s = 0.f;
#pragma unroll
    for (int j = 0; j < DIM; ++j) {
        float c = row[j];
        s = fmaf(c, c, s);
        short hi = f2bf(c);
        short lo = f2bf(c - bf2f(hi));
        cbh[(size_t)k * DIM + j] = hi;
        cbl[(size_t)k * DIM + j] = lo;
    }
    cnorm[k] = s;
}

// --- main: MFMA distance + per-row argmin -------------------------------
// wave = 16 rows; A frags resident; 64 code-tiles of 16; 6 MFMA/tile.
__global__ __launch_bounds__(256) void nsvq_mfma(
    const float* __restrict__ x,
    const short* __restrict__ cbh, const short* __restrict__ cbl,
    const float* __restrict__ cnorm,
    int* __restrict__ bestk_out)
{
    const int lane = threadIdx.x & 63;
    const int wave = threadIdx.x >> 6;
    const int rowBase = blockIdx.x * 64 + wave * 16;
    const int q = lane >> 4;        // quad: k-offset group
    const int n = lane & 15;        // A row (load) / D col (code)

    // A fragments: lane holds A[m=n][k=q*8+j] (+32 for chunk 1)
    bf16x8 a_hi[2], a_lo[2];
    const float* xrow = x + (size_t)(rowBase + n) * DIM + q * 8;
#pragma unroll
    for (int c = 0; c < 2; ++c) {
        const float* p = xrow + c * 32;
#pragma unroll
        for (int j = 0; j < 8; ++j) {
            float f = p[j];
            short hi = f2bf(f);
            a_hi[c][j] = hi;
            a_lo[c][j] = f2bf(f - bf2f(hi));
        }
    }

    float best[4]  = {3.4e38f, 3.4e38f, 3.4e38f, 3.4e38f};
    int   bestk[4] = {0, 0, 0, 0};

#pragma unroll 2
    for (int t = 0; t < KCODES / 16; ++t) {
        const int code = t * 16 + n;
        const size_t boff = (size_t)code * DIM + q * 8;
        // B^T layout: lane holds cb[code][q*8+j] — 16B vector loads
        bf16x8 bh0 = *(const bf16x8*)(cbh + boff);
        bf16x8 bh1 = *(const bf16x8*)(cbh + boff + 32);
        bf16x8 bl0 = *(const bf16x8*)(cbl + boff);
        bf16x8 bl1 = *(const bf16x8*)(cbl + boff + 32);
        float cn = cnorm[code];

        // two independent 3-deep MFMA chains
        f32x4 acc0 = {0.f, 0.f, 0.f, 0.f};
        f32x4 acc1 = {0.f, 0.f, 0.f, 0.f};
        acc0 = __builtin_amdgcn_mfma_f32_16x16x32_bf16(a_hi[0], bh0, acc0, 0, 0, 0);
        acc1 = __builtin_amdgcn_mfma_f32_16x16x32_bf16(a_hi[1], bh1, acc1, 0, 0, 0);
        acc0 = __builtin_amdgcn_mfma_f32_16x16x32_bf16(a_lo[0], bh0, acc0, 0, 0, 0);
        acc1 = __builtin_amdgcn_mfma_f32_16x16x32_bf16(a_lo[1], bh1, acc1, 0, 0, 0);
        acc0 = __builtin_amdgcn_mfma_f32_16x16x32_bf16(a_hi[0], bl0, acc0, 0, 0, 0);
        acc1 = __builtin_amdgcn_mfma_f32_16x16x32_bf16(a_hi[1], bl1, acc1, 0, 0, 0);

#pragma unroll
        for (int r = 0; r < 4; ++r) {
            float d = fmaf(-2.f, acc0[r] + acc1[r], cn);  // ||c||^2 - 2 x.c
            if (d < best[r]) { best[r] = d; bestk[r] = code; }  // first-min tie rule
        }
    }

    // reduce across 16 code-lanes (low 4 bits); D row = q*4 + r
#pragma unroll
    for (int off = 1; off < 16; off <<= 1) {
#pragma unroll
        for (int r = 0; r < 4; ++r) {
            float od = __shfl_xor(best[r], off, 64);
            int   ok = __shfl_xor(bestk[r], off, 64);
            if (od < best[r] || (od == best[r] && ok < bestk[r])) {
                best[r] = od; bestk[r] = ok;
            }
        }
    }
    if (n == 0) {
#pragma unroll
        for (int r = 0; r < 4; ++r)
            bestk_out[rowBase + q * 4 + r] = bestk[r];
    }
}

// --- epilogue: exact fp32 residual + NSVQ output + histogram ------------
// wave = 4 rows x 16 lanes; fully coalesced 1KB/wave accesses.
__global__ __launch_bounds__(256) void nsvq_epilogue(
    const float* __restrict__ x, const float* __restrict__ rv,
    const float* __restrict__ cb, const int* __restrict__ bestk_in,
    float* __restrict__ out, unsigned int* __restrict__ counts)
{
    const int lane = threadIdx.x & 63;
    const int wave = threadIdx.x >> 6;
    const int sub = lane >> 4;       // row within wave
    const int c16 = lane & 15;       // 16 lanes per row
    const int row = (blockIdx.x * 4 + wave) * 4 + sub;
    const size_t off = (size_t)row * DIM + c16 * 4;

    float4 xv  = *(const float4*)(x + off);
    float4 rvv = *(const float4*)(rv + off);
    const int bk = bestk_in[row];                       // broadcast within row
    float4 cv = *(const float4*)(cb + (size_t)bk * DIM + c16 * 4);

    float dx0 = xv.x - cv.x, dx1 = xv.y - cv.y, dx2 = xv.z - cv.z, dx3 = xv.w - cv.w;
    float res = fmaf(dx0, dx0, fmaf(dx1, dx1, fmaf(dx2, dx2, dx3 * dx3)));
    float rr  = fmaf(rvv.x, rvv.x, fmaf(rvv.y, rvv.y, fmaf(rvv.z, rvv.z, rvv.w * rvv.w)));
#pragma unroll
    for (int o = 1; o < 16; o <<= 1) {
        res += __shfl_xor(res, o, 64);
        rr  += __shfl_xor(rr, o, 64);
    }
    float scale = sqrtf(res) / (sqrtf(rr) + 1e-12f);

    float4 ov;
    ov.x = fmaf(scale, rvv.x, xv.x);
    ov.y = fmaf(scale, rvv.y, xv.y);
    ov.z = fmaf(scale, rvv.z, xv.z);
    ov.w = fmaf(scale, rvv.w, xv.w);
    *(float4*)(out + off) = ov;

    if (c16 == 0) atomicAdd(&counts[bk], 1u);
}

// --- finalize: perplexity + counts output -------------------------------
__global__ void nsvq_finalize(const unsigned int* __restrict__ counts,
                              const int* __restrict__ used,
                              float* __restrict__ out)
{
    const int k = threadIdx.x;  // 1024 threads
    const unsigned c = counts[k];
    float avg = (float)c * (1.0f / (float)NROWS);
    float term = (c > 0) ? (-avg * logf(avg + 1e-12f)) : 0.0f;

    float v = term;
#pragma unroll
    for (int o = 32; o > 0; o >>= 1) v += __shfl_down(v, o, 64);

    __shared__ float partial[16];
    if ((threadIdx.x & 63) == 0) partial[threadIdx.x >> 6] = v;
    __syncthreads();

    if (threadIdx.x < 64) {
        float s = (threadIdx.x < 16) ? partial[threadIdx.x] : 0.0f;
#pragma unroll
        for (int o = 32; o > 0; o >>= 1) s += __shfl_down(s, o, 64);
        if (threadIdx.x == 0) out[ND] = expf(s);
    }
    out[ND + 1 + k] = (float)(c + (unsigned)used[k]);
}

extern "C" void kernel_launch(void* const* d_in, const int* in_sizes, int n_in,
                              void* d_out, int out_size, void* d_ws, size_t ws_size,
                              hipStream_t stream) {
    const float* x    = (const float*)d_in[0];
    const float* rv   = (const float*)d_in[1];
    const float* cb   = (const float*)d_in[2];
    const int*   used = (const int*)d_in[3];
    float* out = (float*)d_out;

    char* ws = (char*)d_ws;
    unsigned int* counts = (unsigned int*)ws;                       // 4 KB
    float*        cnorm  = (float*)(ws + 4096);                     // 4 KB
    short*        cbh    = (short*)(ws + 8192);                     // 128 KB
    short*        cbl    = (short*)(ws + 8192 + 131072);            // 128 KB
    int*          bestk  = (int*)(ws + 8192 + 262144);              // 1 MB

    hipMemsetAsync(counts, 0, KCODES * sizeof(unsigned int), stream);
    nsvq_prep<<<(KCODES + 255) / 256, 256, 0, stream>>>(cb, cbh, cbl, cnorm);
    nsvq_mfma<<<NROWS / 64, 256, 0, stream>>>(x, cbh, cbl, cnorm, bestk);
    nsvq_epilogue<<<NROWS / 16, 256, 0, stream>>>(x, rv, cb, bestk, out, counts);
    nsvq_finalize<<<1, KCODES, 0, stream>>>(counts, used, out);
}